// Round 4
// baseline (241.945 us; speedup 1.0000x reference)
//
#include <hip/hip_runtime.h>

// 3D spatial correlation sampler, kernel_size=1, stride=1, pad=0, dil=1, patch=7
// in1,in2: [B=2, C=32, D=32, H=32, W=32] fp32
// out:     [B, 7,7,7, D,H,W] fp32
// out[b,pd,ph,pw,d,h,w] = sum_c in1[b,c,d,h,w] * in2[b,c,d+pd-3,h+ph-3,w+pw-3]
// (zero for OOB reads of in2)

#define BB 2
#define CC 32
#define DD 32
#define HH 32
#define WW 32
#define PP 7
#define RR 3
#define PLANE (HH * WW)          // 1024
#define CH_STRIDE (DD * HH * WW) // 32768
#define NWG (49 * 16 * 2)        // 1568 = 8 * 196
#define NWG_PER_XCD (NWG / 8)    // 196

typedef float f32x4 __attribute__((ext_vector_type(4)));  // native vec for NT stores

__global__ __launch_bounds__(256) void corr3d_kernel(
    const float* __restrict__ in1,
    const float* __restrict__ in2,
    float* __restrict__ out) {
    const int tid = threadIdx.x;
    // XCD-aware swizzle: HW dispatches block j to XCD j%8. Map so that
    // originally-consecutive ids (which share input slabs: 49 offsets per
    // (b,d2)) stay on ONE XCD's private L2.  1568 % 8 == 0 -> bijective.
    const int j = blockIdx.x;
    int bi = (j & 7) * NWG_PER_XCD + (j >> 3);
    const int off = bi % 49; bi /= 49;      // (pd,ph) fastest within an XCD
    const int d2  = bi % 16; bi /= 16;
    const int b   = bi;                     // 0..1
    const int pd  = off / 7;
    const int ph  = off % 7;

    const int wb = tid & 3;                 // w-block 0..3
    const int w0 = wb << 3;                 // 0,8,16,24
    const int h  = (tid >> 2) & 31;
    const int d  = d2 * 2 + (tid >> 7);

    const int dz = d + pd - RR;
    const int hy = h + ph - RR;
    const bool pv = (unsigned)dz < DD;
    const bool rv = (unsigned)hy < HH;

    float acc[8][7];
#pragma unroll
    for (int i = 0; i < 8; ++i)
#pragma unroll
        for (int p = 0; p < 7; ++p) acc[i][p] = 0.f;

    if (pv && rv) {
        const float* p1 = in1 + ((size_t)b * CC * DD + d) * PLANE + h * WW + w0;
        const float* p2 = in2 + ((size_t)b * CC * DD + dz) * PLANE + hy * WW + (w0 - 4);
        const bool lv  = (wb != 0);  // left window block in-range
        const bool rvb = (wb != 3);  // right window block in-range

#pragma unroll 2
        for (int c = 0; c < CC; ++c) {
            const float4 a0 = *(const float4*)(p1);
            const float4 a1 = *(const float4*)(p1 + 4);
            const float4 z  = make_float4(0.f, 0.f, 0.f, 0.f);
            const float4 q0 = lv  ? *(const float4*)(p2)      : z;
            const float4 q1 =       *(const float4*)(p2 + 4);
            const float4 q2 =       *(const float4*)(p2 + 8);
            const float4 q3 = rvb ? *(const float4*)(p2 + 12) : z;

            const float a[8]   = {a0.x, a0.y, a0.z, a0.w, a1.x, a1.y, a1.z, a1.w};
            const float win[16] = {q0.x, q0.y, q0.z, q0.w,
                                   q1.x, q1.y, q1.z, q1.w,
                                   q2.x, q2.y, q2.z, q2.w,
                                   q3.x, q3.y, q3.z, q3.w};
#pragma unroll
            for (int i = 0; i < 8; ++i)
#pragma unroll
                for (int p = 0; p < 7; ++p)
                    acc[i][p] = fmaf(a[i], win[i + p + 1], acc[i][p]);

            p1 += CH_STRIDE;
            p2 += CH_STRIDE;
        }
    }

    // Non-temporal stores: keep the 88 MB output stream from evicting the
    // 16 MB input working set out of the XCD L2.
    float* po = out + (((size_t)(b * 49 + pd * 7 + ph)) * PP) * CH_STRIDE
                    + (size_t)d * PLANE + h * WW + w0;
#pragma unroll
    for (int p = 0; p < 7; ++p) {
        f32x4 lo = {acc[0][p], acc[1][p], acc[2][p], acc[3][p]};
        f32x4 hi = {acc[4][p], acc[5][p], acc[6][p], acc[7][p]};
        __builtin_nontemporal_store(lo, (f32x4*)(po));
        __builtin_nontemporal_store(hi, (f32x4*)(po + 4));
        po += CH_STRIDE;
    }
}

extern "C" void kernel_launch(void* const* d_in, const int* in_sizes, int n_in,
                              void* d_out, int out_size, void* d_ws, size_t ws_size,
                              hipStream_t stream) {
    const float* in1 = (const float*)d_in[0];
    const float* in2 = (const float*)d_in[1];
    float* out = (float*)d_out;
    dim3 grid(NWG);
    dim3 block(256);
    hipLaunchKernelGGL(corr3d_kernel, grid, block, 0, stream, in1, in2, out);
}

// Round 5
// 234.548 us; speedup vs baseline: 1.0315x; 1.0315x over previous
//
#include <hip/hip_runtime.h>

// 3D spatial correlation sampler, kernel_size=1, stride=1, pad=0, dil=1, patch=7
// in1,in2: [B=2, C=32, D=32, H=32, W=32] fp32
// out:     [B, 7,7,7, D,H,W] fp32
// out[b,pd,ph,pw,d,h,w] = sum_c in1[b,c,d,h,w] * in2[b,c,d+pd-3,h+ph-3,w+pw-3]
// (zero for OOB reads of in2)

#define BB 2
#define CC 32
#define DD 32
#define HH 32
#define WW 32
#define PP 7
#define RR 3
#define PLANE (HH * WW)          // 1024
#define CH_STRIDE (DD * HH * WW) // 32768
#define NWG (49 * 16 * 2)        // 1568 = 8 * 196
#define NWG_PER_XCD (NWG / 8)    // 196

// Load one channel's operands into register set A## (6 x float4).
#define LOADC(A, c) do {                                        \
    const float* _p1 = p1 + (size_t)(c) * CH_STRIDE;            \
    const float* _p2 = p2 + (size_t)(c) * CH_STRIDE;            \
    A##a0 = *(const float4*)(_p1);                              \
    A##a1 = *(const float4*)(_p1 + 4);                          \
    A##q0 = lv  ? *(const float4*)(_p2)      : z4;              \
    A##q1 =       *(const float4*)(_p2 + 4);                    \
    A##q2 =       *(const float4*)(_p2 + 8);                    \
    A##q3 = rvb ? *(const float4*)(_p2 + 12) : z4;              \
} while (0)

// 56 FMAs for one channel from register set A##.
#define FMAC(A) do {                                            \
    const float a_[8]   = {A##a0.x, A##a0.y, A##a0.z, A##a0.w,  \
                           A##a1.x, A##a1.y, A##a1.z, A##a1.w}; \
    const float w_[16]  = {A##q0.x, A##q0.y, A##q0.z, A##q0.w,  \
                           A##q1.x, A##q1.y, A##q1.z, A##q1.w,  \
                           A##q2.x, A##q2.y, A##q2.z, A##q2.w,  \
                           A##q3.x, A##q3.y, A##q3.z, A##q3.w}; \
    _Pragma("unroll")                                           \
    for (int i = 0; i < 8; ++i)                                 \
        _Pragma("unroll")                                       \
        for (int p = 0; p < 7; ++p)                             \
            acc[i][p] = fmaf(a_[i], w_[i + p + 1], acc[i][p]);  \
} while (0)

__global__ __launch_bounds__(256) void corr3d_kernel(
    const float* __restrict__ in1,
    const float* __restrict__ in2,
    float* __restrict__ out) {
    const int tid = threadIdx.x;
    // XCD-aware swizzle (kept: FETCH 79->10.5 MB in R4). HW round-robins
    // block j to XCD j%8; remap so originally-consecutive ids (which share
    // input slabs: 49 offsets per (b,d2)) stay on ONE XCD's private L2.
    const int j = blockIdx.x;
    int bi = (j & 7) * NWG_PER_XCD + (j >> 3);
    const int off = bi % 49; bi /= 49;      // (pd,ph) fastest within an XCD
    const int d2  = bi % 16; bi /= 16;
    const int b   = bi;                     // 0..1
    const int pd  = off / 7;
    const int ph  = off % 7;

    const int wb = tid & 3;                 // w-block 0..3
    const int w0 = wb << 3;                 // 0,8,16,24
    const int h  = (tid >> 2) & 31;
    const int d  = d2 * 2 + (tid >> 7);

    const int dz = d + pd - RR;
    const int hy = h + ph - RR;
    const bool pv = (unsigned)dz < DD;
    const bool rv = (unsigned)hy < HH;

    float acc[8][7];
#pragma unroll
    for (int i = 0; i < 8; ++i)
#pragma unroll
        for (int p = 0; p < 7; ++p) acc[i][p] = 0.f;

    if (pv && rv) {
        const float* p1 = in1 + ((size_t)b * CC * DD + d) * PLANE + h * WW + w0;
        const float* p2 = in2 + ((size_t)b * CC * DD + dz) * PLANE + hy * WW + (w0 - 4);
        const bool lv  = (wb != 0);  // left window block in-range
        const bool rvb = (wb != 3);  // right window block in-range
        const float4 z4 = make_float4(0.f, 0.f, 0.f, 0.f);

        float4 Aa0, Aa1, Aq0, Aq1, Aq2, Aq3;
        float4 Ba0, Ba1, Bq0, Bq1, Bq2, Bq3;

        // 1-deep ping-pong software pipeline: issue channel c+1's loads
        // BEFORE channel c's 56 FMAs, so ~200-cyc L2 latency hides under
        // 112 cyc of VALU + other waves. unroll 1 preserves the structure.
        LOADC(A, 0);
#pragma unroll 1
        for (int c = 0; c + 2 < CC; c += 2) {
            LOADC(B, c + 1);
            FMAC(A);
            LOADC(A, c + 2);
            FMAC(B);
        }
        LOADC(B, CC - 1);
        FMAC(A);
        FMAC(B);
    }

    float* po = out + (((size_t)(b * 49 + pd * 7 + ph)) * PP) * CH_STRIDE
                    + (size_t)d * PLANE + h * WW + w0;
#pragma unroll
    for (int p = 0; p < 7; ++p) {
        *(float4*)(po)     = make_float4(acc[0][p], acc[1][p], acc[2][p], acc[3][p]);
        *(float4*)(po + 4) = make_float4(acc[4][p], acc[5][p], acc[6][p], acc[7][p]);
        po += CH_STRIDE;
    }
}

extern "C" void kernel_launch(void* const* d_in, const int* in_sizes, int n_in,
                              void* d_out, int out_size, void* d_ws, size_t ws_size,
                              hipStream_t stream) {
    const float* in1 = (const float*)d_in[0];
    const float* in2 = (const float*)d_in[1];
    float* out = (float*)d_out;
    dim3 grid(NWG);
    dim3 block(256);
    hipLaunchKernelGGL(corr3d_kernel, grid, block, 0, stream, in1, in2, out);
}

// Round 6
// 165.535 us; speedup vs baseline: 1.4616x; 1.4169x over previous
//
#include <hip/hip_runtime.h>

// 3D spatial correlation sampler, kernel_size=1, stride=1, pad=0, dil=1, patch=7
// in1,in2: [B=2, C=32, D=32, H=32, W=32] fp32
// out:     [B, 7,7,7, D,H,W] fp32
// out[b,pd,ph,pw,d,h,w] = sum_c in1[b,c,d,h,w] * in2[b,c,d+pd-3,h+ph-3,w+pw-3]
// (zero for OOB reads of in2)
//
// R6 structure: LDS-staged channels via global_load_lds (dense 1KB DMA),
// double-buffered with counted vmcnt(5) + raw s_barrier (T4 pattern).
// Rationale: R5 showed latency/miss-path bound (VALUBusy 15%, HBM 8%,
// per-thread loads touch half-used 128B lines). DMA staging makes every
// memory request a full-line burst and keeps 10 in flight per wave.

#define BB 2
#define CC 32
#define DD 32
#define HH 32
#define WW 32
#define PP 7
#define RR 3
#define PLANE (HH * WW)          // 1024 floats
#define CH_STRIDE (DD * HH * WW) // 32768 floats
#define NWG (49 * 16 * 2)        // 1568 = 8 * 196
#define NWG_PER_XCD (NWG / 8)    // 196

// LDS layout: 2 buffers x 4 regions (in1 d0, in1 d0+1, in2 dzA, in2 dzB).
// Each region: 32 rows x 144B (128B data + 16B pad col -> bank spread).
// Region staged by one wave as 5 x global_load_lds dwordx4 (5KB incl pad).
#define ROW_BYTES 144
#define REGION_BYTES 5120        // 32*144 = 4608 used, 5120 staged (slack dups)
#define BUF_BYTES (4 * REGION_BYTES)   // 20480
#define LDS_BYTES (2 * BUF_BYTES)      // 40960

__device__ __forceinline__ void stage_channel(
    char* smem, int bf, int c, int wv, int lane,
    int b, int d0, int pd,
    const float* __restrict__ in1, const float* __restrict__ in2) {
    // Each wave stages one 4KB source plane into its 5120B LDS region.
    const float* src;
    if (wv < 2) {
        src = in1 + ((size_t)((b * CC + c) * DD + (d0 + wv))) * PLANE;
    } else {
        int dz = d0 + (wv - 2) + pd - RR;
        dz = dz < 0 ? 0 : (dz > DD - 1 ? DD - 1 : dz);  // clamp; consumers zeroed
        src = in2 + ((size_t)((b * CC + c) * DD + dz)) * PLANE;
    }
    char* dst_base = smem + bf * BUF_BYTES + wv * REGION_BYTES;
#pragma unroll
    for (int i = 0; i < 5; ++i) {
        int q = i * 64 + lane;           // 16B chunk index in padded region
        int row = (q * 57) >> 9;         // == q/9 for q<512 range used
        if (row > 31) row = 31;          // slack chunks re-read last row
        int col = q - row * 9;           // 0..8; col 8 = pad (dup of col 7)
        if (col > 7) col = 7;
        const char* g = (const char*)src + row * 128 + col * 16;
        __builtin_amdgcn_global_load_lds(
            (const __attribute__((address_space(1))) void*)g,
            (__attribute__((address_space(3))) void*)(dst_base + i * 1024),
            16, 0, 0);
    }
}

__global__ __launch_bounds__(256) void corr3d_kernel(
    const float* __restrict__ in1,
    const float* __restrict__ in2,
    float* __restrict__ out) {
    __shared__ __align__(16) char smem[LDS_BYTES];

    const int tid  = threadIdx.x;
    const int lane = tid & 63;
    const int wv   = tid >> 6;

    // XCD-aware swizzle (kept: FETCH 79->10.5 MB). HW round-robins block j
    // to XCD j%8; remap so originally-consecutive ids (49 offsets sharing
    // input slabs per (b,d2)) stay on ONE XCD's private L2.
    const int j = blockIdx.x;
    int bi = (j & 7) * NWG_PER_XCD + (j >> 3);
    const int off = bi % 49; bi /= 49;
    const int d2  = bi % 16; bi /= 16;
    const int b   = bi;
    const int pd  = off / 7;
    const int ph  = off % 7;

    const int wb = tid & 3;              // w-block 0..3
    const int w0 = wb << 3;              // 0,8,16,24
    const int h  = (tid >> 2) & 31;
    const int dd = tid >> 7;             // 0..1
    const int d0 = d2 * 2;
    const int d  = d0 + dd;

    const int dz = d + pd - RR;
    const int hy = h + ph - RR;
    const bool pv = (unsigned)dz < DD;
    const bool rv = (unsigned)hy < HH;
    const int hyc = hy < 0 ? 0 : (hy > HH - 1 ? HH - 1 : hy);
    const bool lv  = (wb != 0);
    const bool rvb = (wb != 3);

    float acc[8][7];
#pragma unroll
    for (int i = 0; i < 8; ++i)
#pragma unroll
        for (int p = 0; p < 7; ++p) acc[i][p] = 0.f;

    // Per-channel LDS read offsets (bytes), invariant across channels.
    const int in1_off = dd * REGION_BYTES + h * ROW_BYTES + (wb * 2) * 16;
    const int in2_row = (2 + dd) * REGION_BYTES + hyc * ROW_BYTES;
    const int c0 = (wb * 2 - 1) < 0 ? 0 : (wb * 2 - 1);  // clamped left col

    stage_channel(smem, 0, 0, wv, lane, b, d0, pd, in1, in2);

#pragma unroll 1
    for (int c = 0; c < CC; ++c) {
        const int bf = c & 1;
        if (c + 1 < CC) {
            stage_channel(smem, bf ^ 1, c + 1, wv, lane, b, d0, pd, in1, in2);
            asm volatile("s_waitcnt vmcnt(5)" ::: "memory");  // stage(c) done; c+1 in flight
        } else {
            asm volatile("s_waitcnt vmcnt(0)" ::: "memory");
        }
        __builtin_amdgcn_s_barrier();    // raw barrier: no vmcnt(0) drain

        const char* bufp = smem + bf * BUF_BYTES;
        const float4 a0 = *(const float4*)(bufp + in1_off);
        const float4 a1 = *(const float4*)(bufp + in1_off + 16);
        const char* r2 = bufp + in2_row;
        float4 q0 = *(const float4*)(r2 + c0 * 16);
        float4 q1 = *(const float4*)(r2 + (wb * 2) * 16);
        float4 q2 = *(const float4*)(r2 + (wb * 2 + 1) * 16);
        float4 q3 = *(const float4*)(r2 + (wb * 2 + 2) * 16); // wb=3 -> pad col
        if (!lv)  q0 = make_float4(0.f, 0.f, 0.f, 0.f);
        if (!rvb) q3 = make_float4(0.f, 0.f, 0.f, 0.f);

        const float a[8]   = {a0.x, a0.y, a0.z, a0.w, a1.x, a1.y, a1.z, a1.w};
        const float win[16] = {q0.x, q0.y, q0.z, q0.w,
                               q1.x, q1.y, q1.z, q1.w,
                               q2.x, q2.y, q2.z, q2.w,
                               q3.x, q3.y, q3.z, q3.w};
#pragma unroll
        for (int i = 0; i < 8; ++i)
#pragma unroll
            for (int p = 0; p < 7; ++p)
                acc[i][p] = fmaf(a[i], win[i + p + 1], acc[i][p]);

        __builtin_amdgcn_s_barrier();    // all reads of bf done before restage
    }

    // OOB (dz/hy) outputs are zero by definition; staged data was clamped
    // garbage (finite), so just zero the accumulators before the store.
    if (!(pv && rv)) {
#pragma unroll
        for (int i = 0; i < 8; ++i)
#pragma unroll
            for (int p = 0; p < 7; ++p) acc[i][p] = 0.f;
    }

    float* po = out + (((size_t)(b * 49 + pd * 7 + ph)) * PP) * CH_STRIDE
                    + (size_t)d * PLANE + h * WW + w0;
#pragma unroll
    for (int p = 0; p < 7; ++p) {
        *(float4*)(po)     = make_float4(acc[0][p], acc[1][p], acc[2][p], acc[3][p]);
        *(float4*)(po + 4) = make_float4(acc[4][p], acc[5][p], acc[6][p], acc[7][p]);
        po += CH_STRIDE;
    }
}

extern "C" void kernel_launch(void* const* d_in, const int* in_sizes, int n_in,
                              void* d_out, int out_size, void* d_ws, size_t ws_size,
                              hipStream_t stream) {
    const float* in1 = (const float*)d_in[0];
    const float* in2 = (const float*)d_in[1];
    float* out = (float*)d_out;
    dim3 grid(NWG);
    dim3 block(256);
    hipLaunchKernelGGL(corr3d_kernel, grid, block, 0, stream, in1, in2, out);
}

// Round 8
// 149.403 us; speedup vs baseline: 1.6194x; 1.1080x over previous
//
#include <hip/hip_runtime.h>

// 3D spatial correlation sampler, kernel_size=1, stride=1, pad=0, dil=1, patch=7
// in1,in2: [B=2, C=32, D=32, H=32, W=32] fp32
// out:     [B, 7,7,7, D,H,W] fp32
// out[b,pd,ph,pw,d,h,w] = sum_c in1[b,c,d,h,w] * in2[b,c,d+pd-3,h+ph-3,w+pw-3]
//
// R8: R7 + sched_barrier(0) fences. Raw s_barrier has NO compiler memory
// semantics; ds_reads could hoist above it (past other waves' staging
// guarantee) -> cross-wave race. sched_barrier(0) pins the LDS reads
// strictly between the two barriers at compile time (zero runtime cost).

#define BB 2
#define CC 32
#define DD 32
#define HH 32
#define WW 32
#define PP 7
#define RR 3
#define PLANE 1024
#define CH_STRIDE 32768
#define CH_BYTES (CH_STRIDE * 4)
#define NWG (49 * 16 * 2)        // 1568 = 8 * 196
#define NWG_PER_XCD (NWG / 8)    // 196

#define ROW_BYTES 176            // 16B left pad | 128B data | 32B right pad
#define REGION_BYTES 6144        // 384 x 16B chunks (32 rows x 176 = 5632 used)
#define BUF_BYTES (2 * REGION_BYTES)   // two dz regions: 12288
#define LDS_BYTES (2 * BUF_BYTES)      // double buffer:  24576

// Stage one channel of in2 (this wave's 3 x 1KB DMA share), then advance.
#define STAGE(BFN) do {                                                        \
    __builtin_amdgcn_global_load_lds(                                          \
        (const __attribute__((address_space(1))) void*)sg0,                    \
        (__attribute__((address_space(3))) void*)(lds_dst + (BFN)*BUF_BYTES),  \
        16, 0, 0);                                                             \
    __builtin_amdgcn_global_load_lds(                                          \
        (const __attribute__((address_space(1))) void*)sg1,                    \
        (__attribute__((address_space(3))) void*)(lds_dst + (BFN)*BUF_BYTES + 1024), \
        16, 0, 0);                                                             \
    __builtin_amdgcn_global_load_lds(                                          \
        (const __attribute__((address_space(1))) void*)sg2,                    \
        (__attribute__((address_space(3))) void*)(lds_dst + (BFN)*BUF_BYTES + 2048), \
        16, 0, 0);                                                             \
    sg0 += CH_BYTES; sg1 += CH_BYTES; sg2 += CH_BYTES;                         \
} while (0)

// 56 FMAs for one channel: in1 from registers R0/R1, in2 window from LDS.
#define COMPUTE(R0, R1, BF) do {                                               \
    const char* bp = smem + (BF) * BUF_BYTES + rdoff;                          \
    float4 q0 = *(const float4*)(bp);                                          \
    float4 q1 = *(const float4*)(bp + 16);                                     \
    float4 q2 = *(const float4*)(bp + 32);                                     \
    float4 q3 = *(const float4*)(bp + 48);                                     \
    if (!lv)  q0 = make_float4(0.f, 0.f, 0.f, 0.f);                            \
    if (!rvb) q3 = make_float4(0.f, 0.f, 0.f, 0.f);                            \
    const float a_[8]    = {R0.x, R0.y, R0.z, R0.w, R1.x, R1.y, R1.z, R1.w};   \
    const float win[16]  = {q0.x, q0.y, q0.z, q0.w, q1.x, q1.y, q1.z, q1.w,    \
                            q2.x, q2.y, q2.z, q2.w, q3.x, q3.y, q3.z, q3.w};   \
    _Pragma("unroll")                                                          \
    for (int i = 0; i < 8; ++i)                                                \
        _Pragma("unroll")                                                      \
        for (int p = 0; p < 7; ++p)                                            \
            acc[i][p] = fmaf(a_[i], win[i + p + 1], acc[i][p]);                \
} while (0)

// Full pipelined phase: stage in2(c+1), prefetch in1(c+1), compute channel c.
// sched_barrier(0) fences: LDS reads must not cross the s_barriers (the raw
// barrier builtin carries no compiler memory semantics).
#define PHASE_FULL(R0, R1, S0, S1, BF) do {                                    \
    STAGE((BF) ^ 1);                                                           \
    S0 = *(const float4*)(p1);                                                 \
    S1 = *(const float4*)(p1 + 4);                                             \
    p1 += CH_STRIDE;                                                           \
    asm volatile("s_waitcnt vmcnt(5)" ::: "memory"); /* c done; c+1 in flight */ \
    __builtin_amdgcn_s_barrier();                                              \
    __builtin_amdgcn_sched_barrier(0);                                         \
    COMPUTE(R0, R1, BF);                                                       \
    __builtin_amdgcn_sched_barrier(0);                                         \
    __builtin_amdgcn_s_barrier();                                              \
} while (0)

#define PHASE_LAST(R0, R1, BF) do {                                            \
    asm volatile("s_waitcnt vmcnt(0)" ::: "memory");                           \
    __builtin_amdgcn_s_barrier();                                              \
    __builtin_amdgcn_sched_barrier(0);                                         \
    COMPUTE(R0, R1, BF);                                                       \
} while (0)

__global__ __launch_bounds__(256) void corr3d_kernel(
    const float* __restrict__ in1,
    const float* __restrict__ in2,
    float* __restrict__ out) {
    __shared__ __align__(16) char smem[LDS_BYTES];

    const int tid  = threadIdx.x;
    const int lane = tid & 63;
    const int wv   = tid >> 6;

    // XCD-aware swizzle (kept: FETCH 79->10.5 MB).
    const int j = blockIdx.x;
    int bi = (j & 7) * NWG_PER_XCD + (j >> 3);
    const int off = bi % 49; bi /= 49;
    const int d2  = bi % 16; bi /= 16;
    const int b   = bi;
    const int pd  = off / 7;
    const int ph  = off % 7;

    const int wb = tid & 3;              // w-block 0..3
    const int w0 = wb << 3;
    const int h  = (tid >> 2) & 31;
    const int dd = tid >> 7;             // 0..1
    const int d0 = d2 * 2;
    const int d  = d0 + dd;

    const int dz = d + pd - RR;
    const int hy = h + ph - RR;
    const bool pv = (unsigned)dz < DD;
    const bool rv = (unsigned)hy < HH;
    const int hyc = hy < 0 ? 0 : (hy > HH - 1 ? HH - 1 : hy);
    const bool lv  = (wb != 0);
    const bool rvb = (wb != 3);

    // ---- per-lane in2 staging sources (channel 0), advanced by CH_BYTES ----
    const int r = wv & 1;                          // region this wave stages
    int dzr = d0 + r + pd - RR;
    dzr = dzr < 0 ? 0 : (dzr > DD - 1 ? DD - 1 : dzr);
    const char* src_plane =
        (const char*)(in2 + ((size_t)(b * CC * DD + dzr)) * PLANE);
    const int qbase = (wv >> 1) * 192 + lane;
    const char* sg0; const char* sg1; const char* sg2;
    {
        // LDS chunk q -> padded row layout: row = q/11, col16 = q%11
        // col16 0 -> left pad (dup byte 0); 1..8 -> data; 9,10 -> right pad.
#define SRCOFF(q, dst) do {                                                    \
        int row_ = ((q) * 5958) >> 16;                                         \
        int c16_ = (q) - row_ * 11;                                            \
        if (row_ > 31) row_ = 31;                                              \
        int colb_ = (c16_ == 0) ? 0 : (c16_ >= 9 ? 112 : (c16_ - 1) * 16);     \
        dst = src_plane + row_ * 128 + colb_;                                  \
} while (0)
        SRCOFF(qbase,        sg0);
        SRCOFF(qbase + 64,   sg1);
        SRCOFF(qbase + 128,  sg2);
#undef SRCOFF
    }
    char* lds_dst = smem + r * REGION_BYTES + (wv >> 1) * 3072;

    // ---- in1 register path (coalesced per-lane, ping-pong prefetch) ----
    const float* p1 = in1 + ((size_t)(b * CC * DD + d)) * PLANE + h * WW + w0;

    // ---- per-thread LDS read offset (channel-invariant) ----
    const int rdoff = dd * REGION_BYTES + hyc * ROW_BYTES + wb * 32;

    float acc[8][7];
#pragma unroll
    for (int i = 0; i < 8; ++i)
#pragma unroll
        for (int p = 0; p < 7; ++p) acc[i][p] = 0.f;

    // prologue: stage c=0 into buf0, load in1(c=0) into A regs
    STAGE(0);
    float4 A0 = *(const float4*)(p1);
    float4 A1 = *(const float4*)(p1 + 4);
    p1 += CH_STRIDE;
    float4 B0, B1;

#pragma unroll 1
    for (int it = 0; it < 15; ++it) {           // channels 0..29
        PHASE_FULL(A0, A1, B0, B1, 0);          // even c: compute buf0
        PHASE_FULL(B0, B1, A0, A1, 1);          // odd  c: compute buf1
    }
    PHASE_FULL(A0, A1, B0, B1, 0);              // c=30 (stages+prefetches c=31)
    PHASE_LAST(B0, B1, 1);                      // c=31

    // OOB (dz/hy) outputs are zero by definition; staged data was clamped
    // garbage (finite), so zero the accumulators before the store.
    if (!(pv && rv)) {
#pragma unroll
        for (int i = 0; i < 8; ++i)
#pragma unroll
            for (int p = 0; p < 7; ++p) acc[i][p] = 0.f;
    }

    float* po = out + (((size_t)(b * 49 + pd * 7 + ph)) * PP) * CH_STRIDE
                    + (size_t)d * PLANE + h * WW + w0;
#pragma unroll
    for (int p = 0; p < 7; ++p) {
        *(float4*)(po)     = make_float4(acc[0][p], acc[1][p], acc[2][p], acc[3][p]);
        *(float4*)(po + 4) = make_float4(acc[4][p], acc[5][p], acc[6][p], acc[7][p]);
        po += CH_STRIDE;
    }
}

extern "C" void kernel_launch(void* const* d_in, const int* in_sizes, int n_in,
                              void* d_out, int out_size, void* d_ws, size_t ws_size,
                              hipStream_t stream) {
    const float* in1 = (const float*)d_in[0];
    const float* in2 = (const float*)d_in[1];
    float* out = (float*)d_out;
    dim3 grid(NWG);
    dim3 block(256);
    hipLaunchKernelGGL(corr3d_kernel, grid, block, 0, stream, in1, in2, out);
}